// Round 4
// baseline (650.422 us; speedup 1.0000x reference)
//
#include <hip/hip_runtime.h>
#include <stdint.h>
#include <stddef.h>

typedef __bf16 bf16;
typedef __attribute__((ext_vector_type(8))) __bf16 bf16x8;
typedef __attribute__((ext_vector_type(4))) __bf16 bf16x4;
typedef __attribute__((ext_vector_type(4))) float f32x4;

#define NN 4096
#define HIDD 512
#define NE 65536

// ---------- async global->LDS, 16B per lane, wave-uniform LDS base ----------
__device__ inline void gll16(const void* g, void* l) {
    __builtin_amdgcn_global_load_lds(
        (const __attribute__((address_space(1))) void*)g,
        (__attribute__((address_space(3))) void*)l, 16, 0, 0);
}

// ---------- fused fp32 -> bf16 convert of w2, w1, W0, W1 (one launch) ----------
__global__ void cvt_all(const float* __restrict__ w2, bf16* __restrict__ o2,
                        const float* __restrict__ w1, bf16* __restrict__ o1,
                        const float* __restrict__ W0, bf16* __restrict__ oW0,
                        const float* __restrict__ W1, bf16* __restrict__ oW1) {
    const int NW = NN * NN;
    const int T1 = 2 * NW;
    const int T2 = T1 + HIDD * NN;
    int i = (blockIdx.x * 256 + threadIdx.x) * 4;
    const float* src; bf16* dst; int k;
    if (i < NW)       { src = w2; dst = o2;  k = i; }
    else if (i < T1)  { src = w1; dst = o1;  k = i - NW; }
    else if (i < T2)  { src = W0; dst = oW0; k = i - T1; }
    else              { src = W1; dst = oW1; k = i - T2; }
    float4 v = *reinterpret_cast<const float4*>(src + k);
    bf16x4 o;
    o[0] = (bf16)v.x; o[1] = (bf16)v.y; o[2] = (bf16)v.z; o[3] = (bf16)v.w;
    *reinterpret_cast<bf16x4*>(dst + k) = o;
}

// ---------- sum S bf16 slices of n elems -> bf16 (n multiple of 2048) ----------
__global__ void reduce_bf16_slices(const bf16* __restrict__ in, bf16* __restrict__ out,
                                   int n, int S) {
    int i = (blockIdx.x * 256 + threadIdx.x) * 8;
    if (i >= n) return;
    float acc[8] = {};
    for (int k = 0; k < S; ++k) {
        bf16x8 v = *reinterpret_cast<const bf16x8*>(in + (size_t)k * n + i);
#pragma unroll
        for (int j = 0; j < 8; ++j) acc[j] += (float)v[j];
    }
    bf16x8 o;
#pragma unroll
    for (int j = 0; j < 8; ++j) o[j] = (bf16)acc[j];
    *reinterpret_cast<bf16x8*>(out + i) = o;
}

// ---------- fp32 transpose -> bf16 with column zero-padding: out[c][r] = in[r][c] ----------
__global__ void transpose_pad_f32(const float* __restrict__ in, bf16* __restrict__ out,
                                  int R, int C, int Cpad) {
    __shared__ bf16 tile[32][33];
    int c0 = blockIdx.x * 32, r0 = blockIdx.y * 32;
    int tx = threadIdx.x, ty = threadIdx.y;
    for (int i = ty; i < 32; i += 8) {
        int r = r0 + i, c = c0 + tx;
        bf16 v = (bf16)0.f;
        if (r < R && c < C) v = (bf16)in[(size_t)r * C + c];
        tile[i][tx] = v;
    }
    __syncthreads();
    for (int i = ty; i < 32; i += 8) {
        int oc = c0 + i, orow = r0 + tx;
        if (oc < Cpad && orow < R) out[(size_t)oc * R + orow] = tile[tx][i];
    }
}

// ---------- fp32 square matrix: one read, write bf16(in^T) and bf16(in) ----------
// 64x64 tile, 256 threads. Phase 1: vector loads + coalesced outD stores + LDS
// (dword writes, stride-66 rows). Phase 2: per-thread column gather from LDS,
// 16B stores with 8 lanes contiguous (128B) per output row.
__global__ void transpose_dual_f32(const float* __restrict__ in, bf16* __restrict__ outT,
                                   bf16* __restrict__ outD, int Nn) {
    __shared__ bf16 tile[64][66];
    int r0 = blockIdx.y * 64, c0 = blockIdx.x * 64;
    int t = threadIdx.x;
    int cg = t & 7, rr = t >> 3;       // 8 col groups of 8; 32 rows per pass
#pragma unroll
    for (int i = 0; i < 2; ++i) {
        int r = rr + i * 32;
        const float* src = in + (size_t)(r0 + r) * Nn + c0 + cg * 8;
        float4 v0 = *reinterpret_cast<const float4*>(src);
        float4 v1 = *reinterpret_cast<const float4*>(src + 4);
        union { bf16x8 b; unsigned int u[4]; } cv;
        cv.b[0] = (bf16)v0.x; cv.b[1] = (bf16)v0.y; cv.b[2] = (bf16)v0.z; cv.b[3] = (bf16)v0.w;
        cv.b[4] = (bf16)v1.x; cv.b[5] = (bf16)v1.y; cv.b[6] = (bf16)v1.z; cv.b[7] = (bf16)v1.w;
        *reinterpret_cast<bf16x8*>(outD + (size_t)(r0 + r) * Nn + c0 + cg * 8) = cv.b;
        unsigned int* tw = reinterpret_cast<unsigned int*>(&tile[r][cg * 8]);
#pragma unroll
        for (int k = 0; k < 4; ++k) tw[k] = cv.u[k];
    }
    __syncthreads();
    int oc = t >> 3, rseg = (t & 7) * 8;
    bf16x8 w0, w1;
#pragma unroll
    for (int e = 0; e < 8; ++e) {
        w0[e] = tile[rseg + e][oc];
        w1[e] = tile[rseg + e][oc + 32];
    }
    *reinterpret_cast<bf16x8*>(outT + (size_t)(c0 + oc) * Nn + r0 + rseg) = w0;
    *reinterpret_cast<bf16x8*>(outT + (size_t)(c0 + oc + 32) * Nn + r0 + rseg) = w1;
}

// ---------- bf16 transpose: out[c][r] = in[r][c], dims multiple of 32 ----------
__global__ void transpose_bf16(const bf16* __restrict__ in, bf16* __restrict__ out,
                               int R, int C) {
    __shared__ bf16 tile[32][33];
    int c0 = blockIdx.x * 32, r0 = blockIdx.y * 32;
    int tx = threadIdx.x, ty = threadIdx.y;
    for (int i = ty; i < 32; i += 8)
        tile[i][tx] = in[(size_t)(r0 + i) * C + c0 + tx];
    __syncthreads();
    for (int i = ty; i < 32; i += 8)
        out[(size_t)(c0 + i) * R + r0 + tx] = tile[tx][i];
}

// ---------- NT GEMM: C[M,N] = A[M,K] * B[N,K]^T ----------
// BM=256, BN=128, BK=32. 4 waves, wave tile 128x64 (acc[8][4]).
// Depth-2 pipeline: 3 LDS buffers (72 KB), 6 gll16 per tile per wave,
// counted s_waitcnt vmcnt(6) -- loads stay in flight across barriers.
// T2 swizzle (16B slot ^ ((row>>1)&3)) applied at global source + LDS read.
// OMODE: 0 = fp32 out at Cp + z*M*N; 1 = bf16 out; 2 = bf16 partial at Cp + z*M*N
// M must be a multiple of 256, N of 128, K/gridDim.z of 32.
template<int OMODE, bool HAS_BIAS, bool ROW_SCALE>
__global__ __launch_bounds__(256, 2)
void gemm_nt(const bf16* __restrict__ A, const bf16* __restrict__ B,
             void* __restrict__ Cp, const float* __restrict__ bias,
             const float* __restrict__ rowscale, int M, int N, int K) {
    __shared__ __align__(16) bf16 As[3][256 * 32];
    __shared__ __align__(16) bf16 Bs[3][128 * 32];
    const int tid  = threadIdx.x;
    const int wave = tid >> 6;
    const int lane = tid & 63;
    const int m0 = blockIdx.y * 256, n0 = blockIdx.x * 128;
    const int lrow = lane >> 2;
    const int lcol = ((lane & 3) ^ ((lane >> 3) & 3)) * 8;   // pre-swizzled source slot
    const int ca = wave * 4;          // A chunks: 16 x 16-row chunks, 4 per wave
    const int cb = wave * 2;          // B chunks: 8 x 16-row chunks, 2 per wave
    size_t arow[4];
#pragma unroll
    for (int q = 0; q < 4; ++q)
        arow[q] = (size_t)(m0 + (ca + q) * 16 + lrow) * K + lcol;
    const size_t brow0 = (size_t)(n0 + cb * 16 + lrow) * K + lcol;
    const size_t brow1 = (size_t)(n0 + (cb + 1) * 16 + lrow) * K + lcol;

    f32x4 acc[8][4] = {};

    const int wm = (wave >> 1) * 128;
    const int wn = (wave & 1) * 64;
    const int fm = wm + (lane & 15);
    const int fn = wn + (lane & 15);
    const int fk = ((lane >> 4) ^ ((lane >> 1) & 3)) * 8;    // swizzled read slot

    const int kper = K / gridDim.z;
    const int kz0 = blockIdx.z * kper;
    const int nt = kper >> 5;

    auto stage = [&](int t, int buf) {
        const int k0 = kz0 + (t << 5);
#pragma unroll
        for (int q = 0; q < 4; ++q)
            gll16(A + arow[q] + k0, &As[buf][(ca + q) * 512]);
        gll16(B + brow0 + k0, &Bs[buf][cb * 512]);
        gll16(B + brow1 + k0, &Bs[buf][(cb + 1) * 512]);
    };

    // prologue: tiles 0 and 1 in flight (12 outstanding vmem ops per wave)
    stage(0, 0);
    if (nt > 1) stage(1, 1);

    int cur = 0;
    for (int t = 0; t < nt; ++t) {
        // wait for tile t only (tile t+1's 6 loads stay in flight)
        if (t + 1 < nt) asm volatile("s_waitcnt vmcnt(6)" ::: "memory");
        else            asm volatile("s_waitcnt vmcnt(0)" ::: "memory");
        __builtin_amdgcn_s_barrier();
        // issue tile t+2 into the buffer freed at the barrier above
        if (t + 2 < nt) {
            int nb = cur + 2; if (nb >= 3) nb -= 3;
            stage(t + 2, nb);
        }
        bf16x8 af[8], bg[4];
#pragma unroll
        for (int i = 0; i < 8; ++i)
            af[i] = *reinterpret_cast<const bf16x8*>(&As[cur][(fm + i * 16) * 32 + fk]);
#pragma unroll
        for (int j = 0; j < 4; ++j)
            bg[j] = *reinterpret_cast<const bf16x8*>(&Bs[cur][(fn + j * 16) * 32 + fk]);
#pragma unroll
        for (int i = 0; i < 8; ++i)
#pragma unroll
            for (int j = 0; j < 4; ++j)
                acc[i][j] = __builtin_amdgcn_mfma_f32_16x16x32_bf16(af[i], bg[j], acc[i][j], 0, 0, 0);
        cur = (cur + 1 == 3) ? 0 : cur + 1;
    }

    const int rbase = m0 + wm + (lane >> 4) * 4;
    const int cbase = n0 + wn + (lane & 15);
    float* outf = (float*)Cp + (size_t)blockIdx.z * M * N;
    bf16*  outb = (bf16*)Cp;
    bf16*  outp = (bf16*)Cp + (size_t)blockIdx.z * M * N;
#pragma unroll
    for (int i = 0; i < 8; ++i) {
#pragma unroll
        for (int j = 0; j < 4; ++j) {
            int col = cbase + j * 16;
            float bv = 0.f;
            if (HAS_BIAS) bv = bias[col];
#pragma unroll
            for (int r = 0; r < 4; ++r) {
                int row = rbase + i * 16 + r;
                float v = acc[i][j][r];
                if (ROW_SCALE) v *= rowscale[row];
                v += bv;
                if (OMODE == 0)      outf[(size_t)row * N + col] = v;
                else if (OMODE == 1) outb[(size_t)row * N + col] = (bf16)v;
                else                 outp[(size_t)row * N + col] = (bf16)v;
            }
        }
    }
}

// ---------- colnorm partials: n2[i] += sum_{a in chunk} (sum of 4 Rf slices)[a,i]*Ht[a,i] ----------
__global__ void colnorm_part(const bf16* __restrict__ Ht, const float* __restrict__ Rf,
                             float* __restrict__ n2) {
    int i = blockIdx.x * 128 + threadIdx.x;   // 32 x-blocks cover 4096 cols
    int a0 = blockIdx.y * 64;                 // 8 y-blocks cover 512 rows
    const size_t n = (size_t)HIDD * NN;
    float s = 0.f;
    for (int a = a0; a < a0 + 64; ++a) {
        size_t idx = (size_t)a * NN + i;
        float r = Rf[idx] + Rf[n + idx] + Rf[2 * n + idx] + Rf[3 * n + idx];
        s += r * (float)Ht[idx];
    }
    atomicAdd(&n2[i], s);
}

// ---------- b' = W1 @ b0 + b1  (one wave per row) ----------
__global__ void bias_fuse(const float* __restrict__ W1, const float* __restrict__ b0,
                          const float* __restrict__ b1, float* __restrict__ bp) {
    int row = blockIdx.x * 4 + (threadIdx.x >> 6);
    int lane = threadIdx.x & 63;
    const float4* wr = (const float4*)(W1 + (size_t)row * HIDD);
    const float4* bz = (const float4*)b0;
    float s = 0.f;
#pragma unroll
    for (int j = 0; j < 2; ++j) {
        float4 a = wr[lane * 2 + j], b = bz[lane * 2 + j];
        s += a.x * b.x + a.y * b.y + a.z * b.z + a.w * b.w;
    }
    for (int off = 32; off; off >>= 1) s += __shfl_down(s, off);
    if (lane == 0) bp[row] = b1[row] + s;
}

// ---------- reduce 4 bf16 slices + rowscale(from n2, inline inv) + colbias -> bf16 ----------
__global__ void reduce4_scale_bias(const bf16* __restrict__ p, bf16* __restrict__ out,
                                   const float* __restrict__ n2, const float* __restrict__ bp) {
    int i = (blockIdx.x * 256 + threadIdx.x) * 8;
    const int n = NN * HIDD;
    float acc[8] = {};
#pragma unroll
    for (int s = 0; s < 4; ++s) {
        bf16x8 v = *reinterpret_cast<const bf16x8*>(p + (size_t)s * n + i);
#pragma unroll
        for (int j = 0; j < 8; ++j) acc[j] += (float)v[j];
    }
    int row = i >> 9;           // HIDD = 512
    int col = i & (HIDD - 1);
    float sc = 1.f / fmaxf(sqrtf(n2[row]), 1e-12f);
    bf16x8 o;
#pragma unroll
    for (int j = 0; j < 8; ++j)
        o[j] = (bf16)(acc[j] * sc + bp[col + j]);
    *reinterpret_cast<bf16x8*>(out + i) = o;
}

// ---------- CSR build ----------
__global__ void csr_count(const int* __restrict__ ei, int* __restrict__ cnt, int E) {
    int e = blockIdx.x * 256 + threadIdx.x;
    if (e < E) atomicAdd(&cnt[ei[e]], 1);
}

__global__ void scan_4096(const int* __restrict__ cnt, int* __restrict__ rs,
                          int* __restrict__ cur) {
    __shared__ int s[1024];
    int t = threadIdx.x;
    int b = t * 4;
    int a0 = cnt[b], a1 = cnt[b + 1], a2 = cnt[b + 2], a3 = cnt[b + 3];
    int tot = a0 + a1 + a2 + a3;
    s[t] = tot;
    __syncthreads();
    for (int off = 1; off < 1024; off <<= 1) {
        int v = (t >= off) ? s[t - off] : 0;
        __syncthreads();
        s[t] += v;
        __syncthreads();
    }
    int excl = s[t] - tot;
    rs[b] = excl; rs[b + 1] = excl + a0; rs[b + 2] = excl + a0 + a1; rs[b + 3] = excl + a0 + a1 + a2;
    cur[b] = excl; cur[b + 1] = excl + a0; cur[b + 2] = excl + a0 + a1; cur[b + 3] = excl + a0 + a1 + a2;
    if (t == 1023) rs[4096] = s[1023];
}

__global__ void csr_scatter(const int* __restrict__ ei, const float* __restrict__ ew,
                            int* __restrict__ cur, int* __restrict__ ccol,
                            float* __restrict__ cw, int E) {
    int e = blockIdx.x * 256 + threadIdx.x;
    if (e < E) {
        int r = ei[e];
        int p = atomicAdd(&cur[r], 1);
        ccol[p] = ei[E + e];
        cw[p] = ew[e];
    }
}

// ---------- one Euler diffusion step in bf16: x' = x + alpha*(Ax - x) + beta*x0 ----------
__global__ void ode_step_bf16(const bf16* __restrict__ xin, const bf16* __restrict__ x0,
                              bf16* __restrict__ xout, const int* __restrict__ rs,
                              const int* __restrict__ ccol, const float* __restrict__ cw,
                              const float* __restrict__ alpha_p, const float* __restrict__ beta_p) {
    int row = blockIdx.x * 4 + (threadIdx.x >> 6);
    int lane = threadIdx.x & 63;
    float alpha = 1.f / (1.f + expf(-alpha_p[0]));
    float beta = beta_p[0];
    const bf16x8* xin8 = (const bf16x8*)xin;
    float acc[8] = {};
    int p0 = rs[row], p1 = rs[row + 1];
    for (int p = p0; p < p1; ++p) {
        int c = ccol[p]; float w = cw[p];
        bf16x8 v = xin8[(size_t)c * 64 + lane];
#pragma unroll
        for (int j = 0; j < 8; ++j) acc[j] += w * (float)v[j];
    }
    bf16x8 xi = xin8[(size_t)row * 64 + lane];
    bf16x8 xz = ((const bf16x8*)x0)[(size_t)row * 64 + lane];
    bf16x8 r;
#pragma unroll
    for (int j = 0; j < 8; ++j) {
        float x = (float)xi[j];
        r[j] = (bf16)(x + alpha * (acc[j] - x) + beta * (float)xz[j]);
    }
    ((bf16x8*)xout)[(size_t)row * 64 + lane] = r;
}

// ---------- epilogue 1: stats of z = relu(nf*x8 + h); column sums + global sum/sumsq ----------
__global__ void epi1(const bf16* __restrict__ x8, const bf16* __restrict__ h,
                     const float* __restrict__ nf_p,
                     float* __restrict__ colsum, float* __restrict__ gst) {
    __shared__ float r1[512], r2[512];
    int b = blockIdx.x, j = threadIdx.x;   // 512 threads, 8 rows/block
    float nf = nf_p[0];
    float cp = 0.f, sq = 0.f;
    for (int i = 0; i < 8; ++i) {
        size_t idx = (size_t)(b * 8 + i) * HIDD + j;
        float v = nf * (float)x8[idx] + (float)h[idx];
        v = fmaxf(v, 0.f);
        cp += v; sq += v * v;
    }
    atomicAdd(&colsum[j], cp);
    r1[j] = cp; r2[j] = sq;
    __syncthreads();
    for (int off = 256; off > 0; off >>= 1) {
        if (j < off) { r1[j] += r1[j + off]; r2[j] += r2[j + off]; }
        __syncthreads();
    }
    if (j == 0) { atomicAdd(&gst[0], r1[0]); atomicAdd(&gst[1], r2[0]); }
}

// ---------- epilogue 2: out = (relu(nf*x8+h) - colmean) / global_std(ddof=1), fp32 ----------
__global__ void epi2(const bf16* __restrict__ x8, const bf16* __restrict__ h,
                     const float* __restrict__ nf_p, const float* __restrict__ colsum,
                     const float* __restrict__ gst, float* __restrict__ out) {
    int i = (blockIdx.x * 256 + threadIdx.x) * 8;
    float nf = nf_p[0];
    float n = (float)NN * (float)HIDD;
    float gmean = gst[0] / n;
    float var = (gst[1] - n * gmean * gmean) / (n - 1.f);
    float istd = rsqrtf(var);
    int col = i & (HIDD - 1);
    bf16x8 xv = *reinterpret_cast<const bf16x8*>(x8 + i);
    bf16x8 hv = *reinterpret_cast<const bf16x8*>(h + i);
    float4 o0, o1;
    float ov[8];
#pragma unroll
    for (int j = 0; j < 8; ++j) {
        float v = fmaxf(nf * (float)xv[j] + (float)hv[j], 0.f);
        float mean = colsum[col + j] * (1.f / (float)NN);
        ov[j] = (v - mean) * istd;
    }
    o0.x = ov[0]; o0.y = ov[1]; o0.z = ov[2]; o0.w = ov[3];
    o1.x = ov[4]; o1.y = ov[5]; o1.z = ov[6]; o1.w = ov[7];
    *reinterpret_cast<float4*>(out + i) = o0;
    *reinterpret_cast<float4*>(out + i + 4) = o1;
}

extern "C" void kernel_launch(void* const* d_in, const int* in_sizes, int n_in,
                              void* d_out, int out_size, void* d_ws, size_t ws_size,
                              hipStream_t stream) {
    const float* knn  = (const float*)d_in[0];
    const float* adj  = (const float*)d_in[1];
    const float* nf   = (const float*)d_in[2];
    const float* w1   = (const float*)d_in[3];
    const float* w2   = (const float*)d_in[4];
    const float* W0   = (const float*)d_in[5];
    const float* b0   = (const float*)d_in[6];
    const float* W1   = (const float*)d_in[7];
    const float* b1   = (const float*)d_in[8];
    const float* ew   = (const float*)d_in[9];
    const float* alph = (const float*)d_in[10];
    const float* beta = (const float*)d_in[11];
    const int*   ei   = (const int*)d_in[12];

    char* w = (char*)d_ws;
    size_t off = 0;
    auto alloc = [&](size_t bytes) -> char* {
        char* p = w + off;
        off += (bytes + 255) & ~(size_t)255;
        return p;
    };
    const size_t SZ_NN  = (size_t)NN * NN * sizeof(bf16);      // 32 MiB
    const size_t SZ_TH  = (size_t)HIDD * NN * sizeof(bf16);    // 4 MiB
    bf16* Bar  = (bf16*)alloc(SZ_NN);                 // adjT bf16
    bf16* Car  = (bf16*)alloc(SZ_NN);                 // w2 bf16 -> ODE x buffers
    bf16* Adjb = (bf16*)alloc(SZ_NN);                 // adj bf16 (straight)
    bf16* W1big= (bf16*)alloc(SZ_NN);                 // w1 bf16
    bf16* knnT = (bf16*)alloc(SZ_TH);
    bf16* tA   = (bf16*)alloc(SZ_TH);
    bf16* tB   = (bf16*)alloc(SZ_TH);                 // ends as H^T
    float* tf  = (float*)alloc((size_t)32 * 1024 * 1024);  // partials / Rf fp32
    bf16* Hm   = (bf16*)alloc(SZ_TH);                 // H [4096,512]
    bf16* W0b  = (bf16*)alloc(SZ_TH);                 // W0 bf16
    bf16* W1sb = (bf16*)alloc((size_t)HIDD * HIDD * sizeof(bf16));
    bf16* Gb   = (bf16*)alloc((size_t)HIDD * HIDD * sizeof(bf16));
    bf16* M0b  = (bf16*)alloc((size_t)HIDD * HIDD * sizeof(bf16));
    bf16* Qtb  = (bf16*)alloc((size_t)HIDD * HIDD * sizeof(bf16));
    bf16* hb   = (bf16*)alloc((size_t)NN * HIDD * sizeof(bf16));  // h in bf16
    float* n2  = (float*)alloc(NN * sizeof(float));
    int*  cnt  = (int*)alloc(NN * sizeof(int));
    int*  rs   = (int*)alloc((NN + 1) * sizeof(int));
    int*  cur  = (int*)alloc(NN * sizeof(int));
    int*  ccol = (int*)alloc(NE * sizeof(int));
    float* cw  = (float*)alloc(NE * sizeof(float));
    float* colsum = (float*)alloc(HIDD * sizeof(float));
    float* gst = (float*)alloc(2 * sizeof(float));
    float* bp  = (float*)alloc(HIDD * sizeof(float));
    bf16* tfb = (bf16*)tf;                            // bf16 partial view of tf
    bf16* xA  = (bf16*)Car;                           // ODE state A (w2b dead by then)
    bf16* xB  = (bf16*)Car + (size_t)NN * HIDD;       // ODE state B
    (void)ws_size; (void)n_in; (void)in_sizes; (void)out_size;

    dim3 tb(32, 8);
    const int nTH = HIDD * NN;      // 2M elems
    const int nHH = HIDD * HIDD;    // 256K elems

    // ---- prep: all dtype converts in one launch; dual transpose of adj ----
    cvt_all<<<35072, 256, 0, stream>>>(w2, Car, w1, W1big, W0, W0b, W1, W1sb);
    transpose_pad_f32<<<dim3(16, 128), tb, 0, stream>>>(knn, knnT, NN, 500, HIDD);
    transpose_dual_f32<<<dim3(64, 64), 256, 0, stream>>>(adj, Bar, Adjb, NN);

    // ---- chain (transposed): t1^T=knn^T w2^T ; t2^T=t1^T adj ; t3^T=t2^T w1^T ; H^T=t3^T adj^T
    // NT with B = {w2, adjT, w1, adj}; split-K=8 bf16 partials in tf, deterministic reduce.
    gemm_nt<2, false, false><<<dim3(32, 2, 8), 256, 0, stream>>>(knnT, Car, tfb, nullptr, nullptr, HIDD, NN, NN);
    reduce_bf16_slices<<<nTH / 2048, 256, 0, stream>>>(tfb, tA, nTH, 8);
    gemm_nt<2, false, false><<<dim3(32, 2, 8), 256, 0, stream>>>(tA, Bar, tfb, nullptr, nullptr, HIDD, NN, NN);
    reduce_bf16_slices<<<nTH / 2048, 256, 0, stream>>>(tfb, tB, nTH, 8);
    gemm_nt<2, false, false><<<dim3(32, 2, 8), 256, 0, stream>>>(tB, W1big, tfb, nullptr, nullptr, HIDD, NN, NN);
    reduce_bf16_slices<<<nTH / 2048, 256, 0, stream>>>(tfb, tA, nTH, 8);
    gemm_nt<2, false, false><<<dim3(32, 2, 8), 256, 0, stream>>>(tA, Adjb, tfb, nullptr, nullptr, HIDD, NN, NN);
    reduce_bf16_slices<<<nTH / 2048, 256, 0, stream>>>(tfb, tB, nTH, 8);   // tB = H^T

    // ---- H [4096,512] ----
    transpose_bf16<<<dim3(128, 16), tb, 0, stream>>>(tB, Hm, HIDD, NN);

    // ---- G = H^T H  [512,512], split-K=32 ----
    gemm_nt<2, false, false><<<dim3(4, 2, 32), 256, 0, stream>>>(tB, tB, tfb, nullptr, nullptr, HIDD, HIDD, NN);
    reduce_bf16_slices<<<nHH / 2048, 256, 0, stream>>>(tfb, Gb, nHH, 32);

    // ---- R^T = G H^T  [512,4096] fp32, split-K=4 (K=512) ----
    gemm_nt<0, false, false><<<dim3(32, 2, 4), 256, 0, stream>>>(Gb, Hm, tf, nullptr, nullptr, HIDD, NN, HIDD);
    // ---- norms: n2[i] = sum_a (sum of R^T slices)[a,i]*H^T[a,i] ----
    hipMemsetAsync(n2, 0, NN * sizeof(float), stream);
    colnorm_part<<<dim3(32, 8), 128, 0, stream>>>(tB, tf, n2);

    // ---- M0 = H^T W0^T  [512,512], split-K=32 ----
    gemm_nt<2, false, false><<<dim3(4, 2, 32), 256, 0, stream>>>(tB, W0b, tfb, nullptr, nullptr, HIDD, HIDD, NN);
    reduce_bf16_slices<<<nHH / 2048, 256, 0, stream>>>(tfb, M0b, nHH, 32);

    // ---- Q^T = W1 M0^T  [512,512], split-K=8 (K=512) ----
    gemm_nt<2, false, false><<<dim3(4, 2, 8), 256, 0, stream>>>(W1sb, M0b, tfb, nullptr, nullptr, HIDD, HIDD, HIDD);
    reduce_bf16_slices<<<nHH / 2048, 256, 0, stream>>>(tfb, Qtb, nHH, 8);

    // ---- b' = W1 b0 + b1 ----
    bias_fuse<<<128, 256, 0, stream>>>(W1, b0, b1, bp);

    // ---- h = diag(inv) H Q + b'  [4096,512] bf16, split-K=4 (K=512) ----
    gemm_nt<2, false, false><<<dim3(4, 16, 4), 256, 0, stream>>>(Hm, Qtb, tfb, nullptr, nullptr, NN, HIDD, HIDD);
    reduce4_scale_bias<<<(NN * HIDD) / 2048, 256, 0, stream>>>(tfb, hb, n2, bp);

    // ---- CSR build ----
    hipMemsetAsync(cnt, 0, NN * sizeof(int), stream);
    csr_count<<<NE / 256, 256, 0, stream>>>(ei, cnt, NE);
    scan_4096<<<1, 1024, 0, stream>>>(cnt, rs, cur);
    csr_scatter<<<NE / 256, 256, 0, stream>>>(ei, ew, cur, ccol, cw, NE);

    // ---- 8 Euler steps (bf16 state): hb -> xA -> xB -> ... -> final in xB ----
    const bf16* xi = hb;
    bf16* xo = xA;
    for (int s = 0; s < 8; ++s) {
        ode_step_bf16<<<NN / 4, 256, 0, stream>>>(xi, hb, xo, rs, ccol, cw, alph, beta);
        xi = xo;
        xo = (s % 2 == 0) ? xB : xA;
    }

    // ---- epilogue ----
    hipMemsetAsync(colsum, 0, HIDD * sizeof(float), stream);
    hipMemsetAsync(gst, 0, 2 * sizeof(float), stream);
    epi1<<<NN / 8, 512, 0, stream>>>(xB, hb, nf, colsum, gst);
    epi2<<<(NN * HIDD) / 2048, 256, 0, stream>>>(xB, hb, nf, colsum, gst, (float*)d_out);
}